// Round 8
// baseline (268.499 us; speedup 1.0000x reference)
//
#include <hip/hip_runtime.h>
#include <math.h>

typedef float f2 __attribute__((ext_vector_type(2)));
typedef float f4 __attribute__((ext_vector_type(4)));

#define NP 110592              // 48^3 voxels
#define OUT1_OFF (192 * NP)    // out0 is 192 planes, out1 follows

// grid: 1296 blocks (= 432 voxel tiles * 3 s), 64 threads, 4 voxels/thread
__global__ __launch_bounds__(64, 2) void recon_kernel(
    const float* __restrict__ xe,   // x_equi_shc  [2][45][NP]
    const float* __restrict__ xiv,  // x_inva_shc  [2][NP]
    const float* __restrict__ pfe,  // polar_filter_equi [2][3][5]
    const float* __restrict__ pfi,  // polar_filter_inva [2][3][1]
    const float* __restrict__ Y,    // [3][64][45]
    float* __restrict__ out)        // out0 [192][NP] ++ out1 [2][3][45][NP]
{
    __shared__ __align__(16) float Yp[64 * 48];  // row-padded Y, c=45 = row-sum
    __shared__ float feS[90];
    __shared__ float gS[2];

    const int tid = threadIdx.x;
    const int bid = blockIdx.x;
    const int s   = bid % 3;   // 3 consecutive blocks share a voxel tile -> L2/L3 reuse on xe
    const int vb  = bid / 3;   // 0..431

    // ---------------- per-block setup ----------------
    for (int i = tid; i < 64 * 45; i += 64) {
        int row = i / 45;
        int c   = i - row * 45;
        Yp[row * 48 + c] = Y[(s * 64 + row) * 45 + c];
    }
    {   // c=45 channel: row sum, computed from global (L2-hot; avoids stride-48 LDS conflicts)
        const float* yrow = Y + (s * 64 + tid) * 45;
        float sum = 0.f;
        #pragma unroll
        for (int c = 0; c < 45; ++c) sum += yrow[c];
        Yp[tid * 48 + 45] = sum;
    }
    for (int i = tid; i < 90; i += 64) {
        int n = i / 45;
        int c = i - n * 45;
        int l = (c == 0) ? 0 : (c < 6) ? 1 : (c < 15) ? 2 : (c < 28) ? 3 : 4;
        feS[i] = pfe[(n * 3 + s) * 5 + l] * sqrtf(4.f * (float)M_PI / (float)(4 * l + 1));
    }
    if (tid < 2) gS[tid] = pfi[tid * 3 + s] * sqrtf(4.f * (float)M_PI);
    __syncthreads();

    // ---------------- main ----------------
    const int p0 = (vb * 64 + tid) * 4;  // this thread's voxel quad (16B aligned)

    f4 tt[46];  // t[c] for 4 voxels; c=45 holds the invariant term u; static indexing only

    const float* xep = xe + p0;
    float* o1 = out + OUT1_OFF + (size_t)s * 45 * NP + p0;  // n=0 base; n=1 at +135*NP

    #pragma unroll
    for (int c = 0; c < 45; ++c) {
        f4 x0 = *(const f4*)(xep + (size_t)c * NP);
        f4 x1 = *(const f4*)(xep + (size_t)(45 + c) * NP);
        f4 v0 = feS[c] * x0;
        f4 v1 = feS[45 + c] * x1;
        __builtin_nontemporal_store(v0, (f4*)(o1 + (size_t)c * NP));
        __builtin_nontemporal_store(v1, (f4*)(o1 + (size_t)(135 + c) * NP));
        tt[c] = v0 + v1;
    }
    {
        f4 a0 = *(const f4*)(xiv + p0);
        f4 a1 = *(const f4*)(xiv + NP + p0);
        tt[45] = gS[0] * a0 + gS[1] * a1;
    }

    // out0: 64 rows, K=46 dot against tt (Y rows broadcast from LDS, wave-uniform addr)
    float* o0 = out + (size_t)s * 64 * NP + p0;
    #pragma unroll 2
    for (int v = 0; v < 64; ++v) {
        const f4* yr = (const f4*)&Yp[v * 48];
        f4 accA = {0.f, 0.f, 0.f, 0.f}, accB = {0.f, 0.f, 0.f, 0.f};
        #pragma unroll
        for (int j = 0; j < 10; j += 2) {
            f4 ya = yr[j];
            f4 yb = yr[j + 1];
            accA += ya.x * tt[4 * j + 0];
            accA += ya.y * tt[4 * j + 1];
            accA += ya.z * tt[4 * j + 2];
            accA += ya.w * tt[4 * j + 3];
            accB += yb.x * tt[4 * j + 4];
            accB += yb.y * tt[4 * j + 5];
            accB += yb.z * tt[4 * j + 6];
            accB += yb.w * tt[4 * j + 7];
        }
        {   // c = 40..43
            f4 ya = yr[10];
            accA += ya.x * tt[40];
            accA += ya.y * tt[41];
            accA += ya.z * tt[42];
            accA += ya.w * tt[43];
        }
        {   // c = 44 + invariant (row-sum * u); 8B-aligned ds_read_b64
            f2 y2 = *(const f2*)&Yp[v * 48 + 44];
            accB += y2.x * tt[44];
            accB += y2.y * tt[45];
        }
        f4 acc = accA + accB;
        __builtin_nontemporal_store(acc, (f4*)(o0 + (size_t)v * NP));
    }
}

extern "C" void kernel_launch(void* const* d_in, const int* in_sizes, int n_in,
                              void* d_out, int out_size, void* d_ws, size_t ws_size,
                              hipStream_t stream) {
    const float* xe  = (const float*)d_in[0];
    const float* xiv = (const float*)d_in[1];
    const float* pfe = (const float*)d_in[2];
    const float* pfi = (const float*)d_in[3];
    const float* Y   = (const float*)d_in[4];
    float* out = (float*)d_out;
    (void)in_sizes; (void)n_in; (void)d_ws; (void)ws_size; (void)out_size;

    recon_kernel<<<dim3(1296), dim3(64), 0, stream>>>(xe, xiv, pfe, pfi, Y, out);
}

// Round 16
// 266.503 us; speedup vs baseline: 1.0075x; 1.0075x over previous
//
#include <hip/hip_runtime.h>
#include <math.h>

typedef float f2 __attribute__((ext_vector_type(2)));
typedef float f4 __attribute__((ext_vector_type(4)));

#define NP 110592              // 48^3 voxels
#define OUT1_OFF (192 * NP)    // out0 is 192 planes, out1 follows

// grid: 1296 blocks (= 432 voxel tiles * 3 s), 64 threads, 4 voxels/thread
__global__ __launch_bounds__(64, 2) void recon_kernel(
    const float* __restrict__ xe,   // x_equi_shc  [2][45][NP]
    const float* __restrict__ xiv,  // x_inva_shc  [2][NP]
    const float* __restrict__ pfe,  // polar_filter_equi [2][3][5]
    const float* __restrict__ pfi,  // polar_filter_inva [2][3][1]
    const float* __restrict__ Y,    // [3][64][45]
    float* __restrict__ out)        // out0 [192][NP] ++ out1 [2][3][45][NP]
{
    __shared__ __align__(16) float Yp[64 * 48];  // row-padded Y, c=45 = row-sum
    __shared__ float feS[90];
    __shared__ float gS[2];

    const int tid = threadIdx.x;
    const int bid = blockIdx.x;
    const int s   = bid % 3;
    const int vb  = bid / 3;   // 0..431

    // ---------------- per-block setup ----------------
    for (int i = tid; i < 64 * 45; i += 64) {
        int row = i / 45;
        int c   = i - row * 45;
        Yp[row * 48 + c] = Y[(s * 64 + row) * 45 + c];
    }
    {   // c=45 channel: row sum (invariant term), from global (L2-hot)
        const float* yrow = Y + (s * 64 + tid) * 45;
        float sum = 0.f;
        #pragma unroll
        for (int c = 0; c < 45; ++c) sum += yrow[c];
        Yp[tid * 48 + 45] = sum;
    }
    for (int i = tid; i < 90; i += 64) {
        int n = i / 45;
        int c = i - n * 45;
        int l = (c == 0) ? 0 : (c < 6) ? 1 : (c < 15) ? 2 : (c < 28) ? 3 : 4;
        feS[i] = pfe[(n * 3 + s) * 5 + l] * sqrtf(4.f * (float)M_PI / (float)(4 * l + 1));
    }
    if (tid < 2) gS[tid] = pfi[tid * 3 + s] * sqrtf(4.f * (float)M_PI);
    __syncthreads();

    // ---------------- main ----------------
    const int p0 = (vb * 64 + tid) * 4;  // this thread's voxel quad (16B aligned)

    f4 tt[46];  // t[c] for 4 voxels; c=45 holds the invariant term u; static indexing only

    const float* xep = xe + p0;
    float* o1 = out + OUT1_OFF + (size_t)s * 45 * NP + p0;  // n=0 base; n=1 at +135*NP

    #pragma unroll
    for (int c = 0; c < 45; ++c) {
        f4 x0 = *(const f4*)(xep + (size_t)c * NP);
        f4 x1 = *(const f4*)(xep + (size_t)(45 + c) * NP);
        f4 v0 = feS[c] * x0;
        f4 v1 = feS[45 + c] * x1;
        *(f4*)(o1 + (size_t)c * NP) = v0;            // plain store (was nontemporal)
        *(f4*)(o1 + (size_t)(135 + c) * NP) = v1;    // plain store (was nontemporal)
        tt[c] = v0 + v1;
    }
    {
        f4 a0 = *(const f4*)(xiv + p0);
        f4 a1 = *(const f4*)(xiv + NP + p0);
        tt[45] = gS[0] * a0 + gS[1] * a1;
    }

    // out0: 64 rows, K=46 dot against tt (Y rows broadcast from LDS, wave-uniform addr)
    float* o0 = out + (size_t)s * 64 * NP + p0;
    #pragma unroll 2
    for (int v = 0; v < 64; ++v) {
        const f4* yr = (const f4*)&Yp[v * 48];
        f4 accA = {0.f, 0.f, 0.f, 0.f}, accB = {0.f, 0.f, 0.f, 0.f};
        #pragma unroll
        for (int j = 0; j < 10; j += 2) {
            f4 ya = yr[j];
            f4 yb = yr[j + 1];
            accA += ya.x * tt[4 * j + 0];
            accA += ya.y * tt[4 * j + 1];
            accA += ya.z * tt[4 * j + 2];
            accA += ya.w * tt[4 * j + 3];
            accB += yb.x * tt[4 * j + 4];
            accB += yb.y * tt[4 * j + 5];
            accB += yb.z * tt[4 * j + 6];
            accB += yb.w * tt[4 * j + 7];
        }
        {   // c = 40..43
            f4 ya = yr[10];
            accA += ya.x * tt[40];
            accA += ya.y * tt[41];
            accA += ya.z * tt[42];
            accA += ya.w * tt[43];
        }
        {   // c = 44 + invariant (row-sum * u)
            f2 y2 = *(const f2*)&Yp[v * 48 + 44];
            accB += y2.x * tt[44];
            accB += y2.y * tt[45];
        }
        f4 acc = accA + accB;
        *(f4*)(o0 + (size_t)v * NP) = acc;           // plain store (was nontemporal)
    }
}

extern "C" void kernel_launch(void* const* d_in, const int* in_sizes, int n_in,
                              void* d_out, int out_size, void* d_ws, size_t ws_size,
                              hipStream_t stream) {
    const float* xe  = (const float*)d_in[0];
    const float* xiv = (const float*)d_in[1];
    const float* pfe = (const float*)d_in[2];
    const float* pfi = (const float*)d_in[3];
    const float* Y   = (const float*)d_in[4];
    float* out = (float*)d_out;
    (void)in_sizes; (void)n_in; (void)d_ws; (void)ws_size; (void)out_size;

    recon_kernel<<<dim3(1296), dim3(64), 0, stream>>>(xe, xiv, pfe, pfi, Y, out);
}